// Round 12
// baseline (198.169 us; speedup 1.0000x reference)
//
#include <hip/hip_runtime.h>
#include <math.h>

// GQA block. Round 15: attn PV widened to K=32 MFMA. The V interleave
// (keys {32u+4q+j, 32u+16+4q+j} per lane) is exactly the 16x16x32 A-frag
// k-mapping, and sv0/sv1 rows land in the matching B-frag lanes -- so PV
// is 4x mfma_16x16x32 per (u,s) instead of 8x mfma_16x16x16 (K=16 runs the
// matrix pipe at half rate). Shufflevector extracts removed. Rest = r14
// (128x128 gemm<0> + fused epilogues, r12 prep/gemm<1>).
// NOTE r14 ran on a ~15% downclocked chip (attn canary 52.4->60.3us); totals
// are cross-run noisy, use attn dur as the clock reference.
// Shapes: B=2, T=2048, DIM=1024, H=16, HKV=4, HD=64.

#define B_   2
#define T_   2048
#define DIM_ 1024
#define NH   16
#define NKV  4
#define HD_  64
#define BT_  (B_ * T_)

typedef _Float16 half8_t __attribute__((ext_vector_type(8)));
typedef _Float16 half4_t __attribute__((ext_vector_type(4)));
typedef float    f32x4   __attribute__((ext_vector_type(4)));

__device__ __forceinline__ void async_copy16(_Float16* lds, const _Float16* g) {
    __builtin_amdgcn_global_load_lds(
        (const __attribute__((address_space(1))) void*)g,
        (__attribute__((address_space(3))) void*)lds, 16, 0, 0);
}

#define VMCNT(n) asm volatile("s_waitcnt vmcnt(" #n ")" ::: "memory")
#define LGKMCNT0() asm volatile("s_waitcnt lgkmcnt(0)" ::: "memory")

__device__ __forceinline__ void wg_barrier() {
    asm volatile("" ::: "memory");
    __builtin_amdgcn_s_barrier();
    asm volatile("" ::: "memory");
}

// ---------------------------------------------------------------------------
// Kernel 1: fused prep, OUTPUT-LINEAR. Block ranges:
//   [0,256): tab; [256,1536): W -> fp16 hi/lo chunks; [1536,3584): A chunks.
// Chunk idx bits: l15[0:3] k8[4:5] u7[6:8] kb[9:13] nb[14:]; holds
// X[nb*128 + u7*16 + l15][kb*32 + k8*8 .. +8].
// ---------------------------------------------------------------------------
__global__ __launch_bounds__(256) void prep_all_kernel(
    float2* __restrict__ tab,
    const float* __restrict__ Wq, const float* __restrict__ Wk,
    const float* __restrict__ Wv, const float* __restrict__ Wo,
    _Float16* __restrict__ Whi, _Float16* __restrict__ Wlo,
    const float* __restrict__ hs, _Float16* __restrict__ Ah)
{
    const int bid = blockIdx.x;
    const int tid = threadIdx.x;
    if (bid < 256) {
        int gid = bid * 256 + tid;                // 0..65535
        int t = gid >> 5, i = gid & 31;
        double invf = pow(10000.0, -(double)i / 32.0);
        double ang  = (double)t * invf;
        tab[gid] = make_float2((float)cos(ang), (float)sin(ang));
    } else if (bid < 1536) {
        int idx = (bid - 256) * 256 + tid;        // 0..327679 output chunk
        int l15 = idx & 15, k8 = (idx >> 4) & 3, u7 = (idx >> 6) & 7;
        int kb = (idx >> 9) & 31, nb = idx >> 14;
        int n = nb * 128 + u7 * 16 + l15, k = kb * 32 + k8 * 8;
        const float* src;
        if (n < 1024)      src = Wq + (size_t)n * 1024;
        else if (n < 1280) src = Wk + (size_t)(n - 1024) * 1024;
        else if (n < 1536) src = Wv + (size_t)(n - 1280) * 1024;
        else               src = Wo + (size_t)(n - 1536) * 1024;
        float4 f0 = *(const float4*)(src + k);
        float4 f1 = *(const float4*)(src + k + 4);
        float xs[8] = {f0.x, f0.y, f0.z, f0.w, f1.x, f1.y, f1.z, f1.w};
        half8_t hi, lo;
#pragma unroll
        for (int j = 0; j < 8; ++j) {
            _Float16 h = (_Float16)xs[j];
            hi[j] = h;
            lo[j] = (_Float16)(xs[j] - (float)h);
        }
        *(half8_t*)&Whi[(size_t)idx * 8] = hi;
        *(half8_t*)&Wlo[(size_t)idx * 8] = lo;
    } else {
        int idx = (bid - 1536) * 256 + tid;       // 0..524287 output chunk
        int l15 = idx & 15, k8 = (idx >> 4) & 3, u7 = (idx >> 6) & 7;
        int kb = (idx >> 9) & 31, mb = idx >> 14;
        const float* src = hs + (size_t)(mb * 128 + u7 * 16 + l15) * 1024
                              + kb * 32 + k8 * 8;
        float4 f0 = *(const float4*)src;
        float4 f1 = *(const float4*)(src + 4);
        half8_t hv;
        hv[0] = (_Float16)f0.x; hv[1] = (_Float16)f0.y;
        hv[2] = (_Float16)f0.z; hv[3] = (_Float16)f0.w;
        hv[4] = (_Float16)f1.x; hv[5] = (_Float16)f1.y;
        hv[6] = (_Float16)f1.z; hv[7] = (_Float16)f1.w;
        *(half8_t*)&Ah[(size_t)idx * 8] = hv;
    }
}

// ---------------------------------------------------------------------------
// Kernel 3: 2-pass MFMA GEMM, all-DMA staging. C = A @ (Whi+Wlo)^T + bias.
// MODE 0: 128x128 tile, 4x4 acc/wave, 2-buf vmcnt(6); fused rope/vth epilogue.
// MODE 1: 128x64 tile, 4x2 acc, 3-buf depth-2 vmcnt(8); row-major fp32 out.
// Both: BK=32, grid x=mb (W-panel L2 reuse), conflict-free 1KiB frag reads.
// B-plane kb stride is ALWAYS 4096 halves (full nb unit).
// ---------------------------------------------------------------------------
template <int MODE>
__global__ __launch_bounds__(256, 3) void gemm2p_kernel(
    const _Float16* __restrict__ Ah,
    const _Float16* __restrict__ Whi, const _Float16* __restrict__ Wlo,
    int nj0,
    const float* __restrict__ bq, const float* __restrict__ bk,
    const float* __restrict__ bv,
    const float2* __restrict__ tab,
    float* __restrict__ o0f,
    _Float16* __restrict__ qh, _Float16* __restrict__ kh,
    _Float16* __restrict__ vth)
{
    constexpr int NBUF = (MODE == 0) ? 2 : 3;
    constexpr int TN   = (MODE == 0) ? 128 : 64;
    constexpr int NT   = TN / 32;         // acc cols per wave
    constexpr int BCH  = TN * 32;         // B halves staged per kb
    __shared__ __align__(16) char smem[49152];
    _Float16 (*sA )[4096] = (_Float16(*)[4096])(smem);
    _Float16 (*sBh)[BCH]  = (_Float16(*)[BCH])(smem + NBUF * 8192);
    _Float16 (*sBl)[BCH]  = (_Float16(*)[BCH])(smem + NBUF * 8192 + NBUF * BCH * 2);

    const int tid  = threadIdx.x;
    const int w    = tid >> 6, lane = tid & 63;
    const int quad = lane >> 4, l15 = lane & 15;
    const int wm = w >> 1, wn = w & 1;
    const int mb   = blockIdx.x;          // x = row tile (W-panel L2 reuse)
    const int nblk = blockIdx.y;

    const _Float16* AB = Ah + (size_t)mb * 32 * 4096;
    size_t woff;
    if constexpr (MODE == 0) {
        woff = (size_t)nblk * 32 * 4096;                    // nb = nblk (128-col)
    } else {
        int nj = nj0 + nblk;                                // 64-col index
        woff = (size_t)(nj >> 1) * 32 * 4096 + (size_t)(nj & 1) * 2048;
    }
    const _Float16* WhiB = Whi + woff;
    const _Float16* WloB = Wlo + woff;

    f32x4 acc[4][NT];
#pragma unroll
    for (int mt = 0; mt < 4; ++mt)
#pragma unroll
        for (int nt = 0; nt < NT; ++nt) {
            f32x4 z = {0.f, 0.f, 0.f, 0.f};
            acc[mt][nt] = z;
        }

#define GEMM_STAGE(buf, kbl)                                                  \
    {                                                                         \
        const _Float16* ga = AB   + (size_t)(kbl) * 4096;                     \
        const _Float16* gh = WhiB + (size_t)(kbl) * 4096;                     \
        const _Float16* gl = WloB + (size_t)(kbl) * 4096;                     \
        int cb = w * 64;                                                      \
        async_copy16(&sA [buf][cb * 8],         ga + (size_t)(cb + lane) * 8);        \
        async_copy16(&sA [buf][(cb + 256) * 8], ga + (size_t)(cb + 256 + lane) * 8);  \
        async_copy16(&sBh[buf][cb * 8],         gh + (size_t)(cb + lane) * 8);        \
        async_copy16(&sBl[buf][cb * 8],         gl + (size_t)(cb + lane) * 8);        \
        if constexpr (TN == 128) {                                            \
            async_copy16(&sBh[buf][(cb + 256) * 8], gh + (size_t)(cb + 256 + lane) * 8); \
            async_copy16(&sBl[buf][(cb + 256) * 8], gl + (size_t)(cb + 256 + lane) * 8); \
        }                                                                     \
    }

    if constexpr (MODE == 0) {
        GEMM_STAGE(0, 0);
    } else {
        GEMM_STAGE(0, 0);
        GEMM_STAGE(1, 1);
    }

    for (int kb = 0; kb < 32; ++kb) {
        const int cur = (MODE == 0) ? (kb & 1) : (kb % 3);
        if constexpr (MODE == 0) {
            if (kb + 1 < 32) {
                GEMM_STAGE(cur ^ 1, kb + 1);
                VMCNT(6);       // stage(kb) done; stage(kb+1) in flight
            } else {
                VMCNT(0);
            }
        } else {
            if (kb + 2 < 32) {
                GEMM_STAGE((kb + 2) % 3, kb + 2);
                VMCNT(8);       // stage(kb) done; kb+1, kb+2 in flight
            } else if (kb + 1 < 32) {
                VMCNT(4);
            } else {
                VMCNT(0);
            }
        }
        wg_barrier();

        half8_t af[4], bf[NT], blv[NT];
#pragma unroll
        for (int mt = 0; mt < 4; ++mt)
            af[mt] = *(const half8_t*)&sA[cur][(((wm * 4 + mt) * 64) + lane) * 8];
#pragma unroll
        for (int nt = 0; nt < NT; ++nt) {
            bf[nt]  = *(const half8_t*)&sBh[cur][(((wn * NT + nt) * 64) + lane) * 8];
            blv[nt] = *(const half8_t*)&sBl[cur][(((wn * NT + nt) * 64) + lane) * 8];
        }
#pragma unroll
        for (int mt = 0; mt < 4; ++mt)
#pragma unroll
            for (int nt = 0; nt < NT; ++nt) {
                acc[mt][nt] = __builtin_amdgcn_mfma_f32_16x16x32_f16(af[mt], bf[nt],  acc[mt][nt], 0, 0, 0);
                acc[mt][nt] = __builtin_amdgcn_mfma_f32_16x16x32_f16(af[mt], blv[nt], acc[mt][nt], 0, 0, 0);
            }
        LGKMCNT0();             // LDS reads of buf[cur] retired
        wg_barrier();           // safe for next stage to overwrite buf[cur]
    }

    if constexpr (MODE == 0) {
        // 128-col tile = 2 same-kind heads; this wave's head = hbase + wn.
        const float* bias; int kind, hbase;
        if (nblk < 8)       { bias = bq; kind = 0; hbase = nblk * 2; }
        else if (nblk < 10) { bias = bk; kind = 1; hbase = (nblk - 8) * 2; }
        else                { bias = bv; kind = 2; hbase = (nblk - 10) * 2; }
        const int b_ = mb >> 4;
        const int hh = hbase + wn;
        float bias4[NT];
#pragma unroll
        for (int nt = 0; nt < NT; ++nt)
            bias4[nt] = bias[hh * 64 + nt * 16 + l15];

        if (kind == 2) {
            // vth unit (u = 2wm+j, dt = nt) per (j,nt); keys {32u+4quad+r, +16+r}.
            const int kt2 = mb & 15;
            _Float16* base = vth + ((size_t)(b_ * NKV + hh) * 16 + kt2) * 8192;
#pragma unroll
            for (int j = 0; j < 2; ++j)
#pragma unroll
                for (int nt = 0; nt < NT; ++nt) {
                    int u = wm * 2 + j, dt = nt;
                    half8_t hv;
#pragma unroll
                    for (int r = 0; r < 4; ++r) {
                        hv[r]     = (_Float16)(acc[2 * j][nt][r]     + bias4[nt]);
                        hv[4 + r] = (_Float16)(acc[2 * j + 1][nt][r] + bias4[nt]);
                    }
                    int c = u * 256 + dt * 64 + quad * 16 + l15;
                    *(half8_t*)(base + (size_t)c * 8) = hv;
                }
        } else {
            // two 64-col half-passes: hp selects head hbase+hp; writers wn==hp.
            float* tile = (float*)smem;         // 128x64 fp32 = 32KB
#pragma unroll
            for (int hp = 0; hp < 2; ++hp) {
                __syncthreads();
                if (wn == hp) {
#pragma unroll
                    for (int mt = 0; mt < 4; ++mt)
#pragma unroll
                        for (int nt = 0; nt < NT; ++nt)
#pragma unroll
                            for (int r = 0; r < 4; ++r) {
                                int rr  = wm * 64 + mt * 16 + quad * 4 + r;
                                int col = nt * 16 + l15;
                                int sc_ = col ^ (((rr >> 2) & 7) << 2);
                                tile[rr * 64 + sc_] = acc[mt][nt][r] + bias4[nt];
                            }
                }
                __syncthreads();
                // rope: thread = (row rr, half ih); i = 16*ih + ii
                const int rr = tid >> 1, ih = tid & 1;
                const int t_ = (mb & 15) * 128 + rr;
                const int swz = ((rr >> 2) & 7) << 2;
                const float* trow = tile + rr * 64;
                const float sc = (kind == 0) ? 0.125f : 1.0f;
                const int h2 = hbase + hp;
                _Float16* dst = ((kind == 0) ? qh : kh) +
                    ((size_t)(b_ * ((kind == 0) ? NH : NKV) + h2) * T_ + t_) * 64;
                half8_t lo0, lo1, hi0, hi1;
#pragma unroll
                for (int ii = 0; ii < 16; ++ii) {
                    int i = ih * 16 + ii;
                    float2 cs = tab[t_ * 32 + i];
                    float x0 = trow[i ^ swz];
                    float x1 = trow[(i + 32) ^ swz];
                    float xe = trow[(2 * i) ^ swz];
                    float xo = trow[(2 * i + 1) ^ swz];
                    float olo = (x0 * cs.x - xo * cs.y) * sc;
                    float ohi = (x1 * cs.x + xe * cs.y) * sc;
                    if (ii < 8) { lo0[ii] = (_Float16)olo; hi0[ii] = (_Float16)ohi; }
                    else        { lo1[ii - 8] = (_Float16)olo; hi1[ii - 8] = (_Float16)ohi; }
                }
                *(half8_t*)(dst + ih * 16)          = lo0;
                *(half8_t*)(dst + ih * 16 + 8)      = lo1;
                *(half8_t*)(dst + 32 + ih * 16)     = hi0;
                *(half8_t*)(dst + 32 + ih * 16 + 8) = hi1;
            }
        }
    } else {
        const int m0 = mb * 128;
        int n0 = nblk * 64 + wn * 32;
#pragma unroll
        for (int mt = 0; mt < 4; ++mt)
#pragma unroll
            for (int r = 0; r < 4; ++r) {
                int m = m0 + wm * 64 + mt * 16 + quad * 4 + r;
#pragma unroll
                for (int nt = 0; nt < NT; ++nt) {
                    int n = n0 + nt * 16 + l15;
                    o0f[(size_t)m * 1024 + n] = acc[mt][nt][r] + bq[n];
                }
            }
    }
#undef GEMM_STAGE
}

// ---------------------------------------------------------------------------
// Kernel 6: flash attention, 128 q/block, 32 q/wave, KVBLK=128.
// PV now K=32: sv0/sv1 (keys 32u+4q+r and 32u+16+4q+r) exp'd into one half8
// pb8 whose lane/elem mapping matches the interleaved av8 A-frag -> 4x
// mfma_16x16x32 per (u,s) replaces 8x mfma_16x16x16 (half-rate K=16).
// ---------------------------------------------------------------------------
__global__ __launch_bounds__(256, 2) void attn_kernel(
    const _Float16* __restrict__ qh, const _Float16* __restrict__ kh,
    const _Float16* __restrict__ vth, _Float16* __restrict__ ctx_h)
{
    __shared__ _Float16 Ks[2][8192];
    __shared__ _Float16 Vs[2][8192];

    const int qt = blockIdx.x;          // 0..15 (128-q tiles)
    const int bh = blockIdx.y;          // 0..31
    const int b  = bh >> 4, h = bh & 15, hk = h >> 2;
    const int tid  = threadIdx.x;
    const int w    = tid >> 6;
    const int lane = tid & 63;
    const int quad = lane >> 4, l15 = lane & 15;

    // Q B-frags for 2 strips of 16 q-rows (q pre-scaled by 0.125 at rope)
    half8_t aq0[2], aq1[2];
#pragma unroll
    for (int s = 0; s < 2; ++s) {
        const _Float16* Qb = qh +
            ((size_t)(b * NH + h) * T_ + qt * 128 + w * 32 + s * 16 + l15) * 64 + quad * 8;
        aq0[s] = *(const half8_t*)(Qb);
        aq1[s] = *(const half8_t*)(Qb + 32);
    }
    // Force Q loads resolved here -> no compiler vmcnt waits inside the loop.
    asm volatile("" :: "v"(aq0[0]), "v"(aq0[1]), "v"(aq1[0]), "v"(aq1[1]));

    const _Float16* Kb = kh  + (size_t)(b * NKV + hk) * (T_ * 64);
    const _Float16* Vb = vth + (size_t)(b * NKV + hk) * (64 * T_);

    // Stage one 128-key tile-pair: K 1024 chunks + V 1024 chunks, 8 DMA/thread.
#define ATTN_STAGE(buf, ktile)                                                \
    {                                                                         \
        _Float16* kd = &Ks[buf][0];                                           \
        _Float16* vd = &Vs[buf][0];                                           \
        _Pragma("unroll")                                                     \
        for (int p = 0; p < 4; ++p) {                                         \
            int cb = p * 256 + w * 64;                                        \
            int c  = cb + lane;                                               \
            int kl = c & 15, kq = (c >> 4) & 3, ktt = (c >> 6) & 7, kr = c >> 9; \
            const _Float16* kg = Kb + ((size_t)((ktile) * 128 + ktt * 16 + kl)) * 64 + (kr * 4 + kq) * 8; \
            const _Float16* vg = Vb + ((size_t)(ktile) * 1024 + c) * 8;       \
            async_copy16(kd + cb * 8, kg);                                    \
            async_copy16(vd + cb * 8, vg);                                    \
        }                                                                     \
    }

    float l_i[2] = {0.0f, 0.0f};
    f32x4 o_acc[2][4];
#pragma unroll
    for (int s = 0; s < 2; ++s)
#pragma unroll
        for (int dt = 0; dt < 4; ++dt) { f32x4 z = {0.f,0.f,0.f,0.f}; o_acc[s][dt] = z; }

    ATTN_STAGE(0, 0);

    for (int kt = 0; kt < T_ / 128; ++kt) {
        const int cur = kt & 1;
        if (kt + 1 < T_ / 128) {
            ATTN_STAGE(cur ^ 1, kt + 1);
            VMCNT(8);           // wait stage(cur) only; stage(next) in flight
        } else {
            VMCNT(0);
        }
        wg_barrier();           // buf[cur] ready across all waves

#pragma unroll
        for (int u = 0; u < 4; ++u) {
            // K frags for t=2u, 2u+1: wave-contiguous 1KiB b128 reads
            half8_t ak0[2], ak1[2];
#pragma unroll
            for (int tt = 0; tt < 2; ++tt) {
                const _Float16* kr_ = &Ks[cur][((2 * u + tt) * 64 + lane) * 8];
                ak0[tt] = *(const half8_t*)(kr_);
                ak1[tt] = *(const half8_t*)(kr_ + 4096);
            }
            // V A-frags (16x16x32): av8[dt][j] = V^T[d=16dt+l15][K(quad,j)]
            // with K(q,j) = 32u+4q+j (j<4) / 32u+16+4q+j-4 (j>=4).
            half8_t av8[4];
#pragma unroll
            for (int dt = 0; dt < 4; ++dt)
                av8[dt] = *(const half8_t*)&Vs[cur][((u * 4 + dt) * 64 + lane) * 8];

#pragma unroll
            for (int s = 0; s < 2; ++s) {
                // S^T for both 16-key halves of the 32-key u-group
                f32x4 z0 = {0.f,0.f,0.f,0.f}, z1 = {0.f,0.f,0.f,0.f};
                z0 = __builtin_amdgcn_mfma_f32_16x16x32_f16(ak0[0], aq0[s], z0, 0, 0, 0);
                f32x4 sv0 = __builtin_amdgcn_mfma_f32_16x16x32_f16(ak1[0], aq1[s], z0, 0, 0, 0);
                z1 = __builtin_amdgcn_mfma_f32_16x16x32_f16(ak0[1], aq0[s], z1, 0, 0, 0);
                f32x4 sv1 = __builtin_amdgcn_mfma_f32_16x16x32_f16(ak1[1], aq1[s], z1, 0, 0, 0);
                // P: lane (quad,l15) elem j holds exactly P[K(quad,j)][q=l15]
                float p0 = __expf(sv0[0]), p1 = __expf(sv0[1]);
                float p2 = __expf(sv0[2]), p3 = __expf(sv0[3]);
                float p4 = __expf(sv1[0]), p5 = __expf(sv1[1]);
                float p6 = __expf(sv1[2]), p7 = __expf(sv1[3]);
                l_i[s] += ((p0 + p1) + (p2 + p3)) + ((p4 + p5) + (p6 + p7));
                half8_t pb8;
                pb8[0] = (_Float16)p0; pb8[1] = (_Float16)p1;
                pb8[2] = (_Float16)p2; pb8[3] = (_Float16)p3;
                pb8[4] = (_Float16)p4; pb8[5] = (_Float16)p5;
                pb8[6] = (_Float16)p6; pb8[7] = (_Float16)p7;
#pragma unroll
                for (int dt = 0; dt < 4; ++dt)
                    o_acc[s][dt] = __builtin_amdgcn_mfma_f32_16x16x32_f16(
                        av8[dt], pb8, o_acc[s][dt], 0, 0, 0);
            }
        }
        LGKMCNT0();             // all LDS reads of buf[cur] retired
        wg_barrier();           // safe for next iter's DMA to overwrite
    }

    // epilogue: reduce l across quads, normalize, packed half4 ctx stores.
    const int mb = b * 16 + qt;
#pragma unroll
    for (int s = 0; s < 2; ++s) {
        float l = l_i[s];
        l += __shfl_xor(l, 16);
        l += __shfl_xor(l, 32);
        float inv = 1.0f / l;
#pragma unroll
        for (int dt = 0; dt < 4; ++dt) {
            int kb_ = 2 * h + (dt >> 1);
            int k8  = (2 * dt + (quad >> 1)) & 3;
            size_t idx = (size_t)(mb * 32 + kb_) * 512 + (w * 2 + s) * 64 + k8 * 16 + l15;
            half4_t hv;
#pragma unroll
            for (int r = 0; r < 4; ++r)
                hv[r] = (_Float16)(o_acc[s][dt][r] * inv);
            *(half4_t*)&ctx_h[idx * 8 + 4 * (quad & 1)] = hv;
        }
    }
#undef ATTN_STAGE
}

// ---------------------------------------------------------------------------
extern "C" void kernel_launch(void* const* d_in, const int* in_sizes, int n_in,
                              void* d_out, int out_size, void* d_ws, size_t ws_size,
                              hipStream_t stream)
{
    const float* hs = (const float*)d_in[0];
    const float* Wq = (const float*)d_in[1];
    const float* bq = (const float*)d_in[2];
    const float* Wk = (const float*)d_in[3];
    const float* bk = (const float*)d_in[4];
    const float* Wv = (const float*)d_in[5];
    const float* bv = (const float*)d_in[6];
    const float* Wo = (const float*)d_in[7];
    const float* bo = (const float*)d_in[8];
    float* out = (float*)d_out;

    const size_t MB = 1024 * 1024;
    if (ws_size < 46 * MB) return;

    char* w = (char*)d_ws;
    _Float16* Whi  = (_Float16*)(w);              // 5 MB  [0,5)
    _Float16* Wlo  = (_Float16*)(w + 5 * MB);     // 5 MB  [5,10)
    _Float16* hs_h = (_Float16*)(w + 10 * MB);    // 8 MB  [10,18) A chunks
    _Float16* qh   = (_Float16*)(w + 18 * MB);    // 8 MB  [18,26)
    _Float16* kh   = (_Float16*)(w + 26 * MB);    // 2 MB  [26,28)
    _Float16* vth  = (_Float16*)(w + 28 * MB);    // 2 MB  [28,30)
    float2*   tab  = (float2*)(w + 30 * MB);      // 0.5MB [30,30.5)
    // ctx aliases hs_h: A chunks dead once gemm<0> completes; attn (which
    // writes ctx) runs strictly after.
    _Float16* ctx_h = hs_h;

    prep_all_kernel<<<3584, 256, 0, stream>>>(
        tab, Wq, Wk, Wv, Wo, Whi, Wlo, hs, hs_h);
    gemm2p_kernel<0><<<dim3(32, 12), 256, 0, stream>>>(
        hs_h, Whi, Wlo, 0, bq, bk, bv, tab, nullptr, qh, kh, vth);
    attn_kernel<<<dim3(T_ / 128, B_ * NH), 256, 0, stream>>>(qh, kh, vth, ctx_h);
    gemm2p_kernel<1><<<dim3(32, 16), 256, 0, stream>>>(
        ctx_h, Whi, Wlo, 24, bo, nullptr, nullptr, tab, out, nullptr, nullptr, nullptr);
}

// Round 13
// 168.375 us; speedup vs baseline: 1.1770x; 1.1770x over previous
//
#include <hip/hip_runtime.h>
#include <math.h>

// GQA block. Round 16: (a) revert GEMMs to r12 geometry -- 128x64 tile,
// 3-buf depth-2, grids 32x24 / 32x16 = 3.0 / 2.0 blocks/CU EXACTLY BALANCED
// (r13-15's 128x128 grid 32x12=384 blocks left half the CUs with 2 blocks,
// half with 1 -> 4:3 imbalance, +10us non-attn regression at equal clock).
// (b) drop the Wlo plane: A is already single-plane fp16 (absmax 2.4e-4);
// W single-plane adds comparable rounding -> predicted absmax 3.5-5e-4 vs
// threshold 1.18e-3. Halves GEMM MFMA work, cuts staging DMA 25%.
// (c) attn = r15 (PV K=32, 51.3us, 0 conflicts) unchanged.
// Shapes: B=2, T=2048, DIM=1024, H=16, HKV=4, HD=64.

#define B_   2
#define T_   2048
#define DIM_ 1024
#define NH   16
#define NKV  4
#define HD_  64
#define BT_  (B_ * T_)

typedef _Float16 half8_t __attribute__((ext_vector_type(8)));
typedef _Float16 half4_t __attribute__((ext_vector_type(4)));
typedef float    f32x4   __attribute__((ext_vector_type(4)));

__device__ __forceinline__ void async_copy16(_Float16* lds, const _Float16* g) {
    __builtin_amdgcn_global_load_lds(
        (const __attribute__((address_space(1))) void*)g,
        (__attribute__((address_space(3))) void*)lds, 16, 0, 0);
}

#define VMCNT(n) asm volatile("s_waitcnt vmcnt(" #n ")" ::: "memory")
#define LGKMCNT0() asm volatile("s_waitcnt lgkmcnt(0)" ::: "memory")

__device__ __forceinline__ void wg_barrier() {
    asm volatile("" ::: "memory");
    __builtin_amdgcn_s_barrier();
    asm volatile("" ::: "memory");
}

// ---------------------------------------------------------------------------
// Kernel 1: fused prep, OUTPUT-LINEAR. Block ranges:
//   [0,256): tab; [256,1536): W -> fp16 chunks (single plane);
//   [1536,3584): A chunks.
// Chunk idx bits: l15[0:3] k8[4:5] u7[6:8] kb[9:13] nb[14:]; holds
// X[nb*128 + u7*16 + l15][kb*32 + k8*8 .. +8].
// ---------------------------------------------------------------------------
__global__ __launch_bounds__(256) void prep_all_kernel(
    float2* __restrict__ tab,
    const float* __restrict__ Wq, const float* __restrict__ Wk,
    const float* __restrict__ Wv, const float* __restrict__ Wo,
    _Float16* __restrict__ Whi,
    const float* __restrict__ hs, _Float16* __restrict__ Ah)
{
    const int bid = blockIdx.x;
    const int tid = threadIdx.x;
    if (bid < 256) {
        int gid = bid * 256 + tid;                // 0..65535
        int t = gid >> 5, i = gid & 31;
        double invf = pow(10000.0, -(double)i / 32.0);
        double ang  = (double)t * invf;
        tab[gid] = make_float2((float)cos(ang), (float)sin(ang));
    } else if (bid < 1536) {
        int idx = (bid - 256) * 256 + tid;        // 0..327679 output chunk
        int l15 = idx & 15, k8 = (idx >> 4) & 3, u7 = (idx >> 6) & 7;
        int kb = (idx >> 9) & 31, nb = idx >> 14;
        int n = nb * 128 + u7 * 16 + l15, k = kb * 32 + k8 * 8;
        const float* src;
        if (n < 1024)      src = Wq + (size_t)n * 1024;
        else if (n < 1280) src = Wk + (size_t)(n - 1024) * 1024;
        else if (n < 1536) src = Wv + (size_t)(n - 1280) * 1024;
        else               src = Wo + (size_t)(n - 1536) * 1024;
        float4 f0 = *(const float4*)(src + k);
        float4 f1 = *(const float4*)(src + k + 4);
        half8_t hi;
        hi[0] = (_Float16)f0.x; hi[1] = (_Float16)f0.y;
        hi[2] = (_Float16)f0.z; hi[3] = (_Float16)f0.w;
        hi[4] = (_Float16)f1.x; hi[5] = (_Float16)f1.y;
        hi[6] = (_Float16)f1.z; hi[7] = (_Float16)f1.w;
        *(half8_t*)&Whi[(size_t)idx * 8] = hi;
    } else {
        int idx = (bid - 1536) * 256 + tid;       // 0..524287 output chunk
        int l15 = idx & 15, k8 = (idx >> 4) & 3, u7 = (idx >> 6) & 7;
        int kb = (idx >> 9) & 31, mb = idx >> 14;
        const float* src = hs + (size_t)(mb * 128 + u7 * 16 + l15) * 1024
                              + kb * 32 + k8 * 8;
        float4 f0 = *(const float4*)src;
        float4 f1 = *(const float4*)(src + 4);
        half8_t hv;
        hv[0] = (_Float16)f0.x; hv[1] = (_Float16)f0.y;
        hv[2] = (_Float16)f0.z; hv[3] = (_Float16)f0.w;
        hv[4] = (_Float16)f1.x; hv[5] = (_Float16)f1.y;
        hv[6] = (_Float16)f1.z; hv[7] = (_Float16)f1.w;
        *(half8_t*)&Ah[(size_t)idx * 8] = hv;
    }
}

// ---------------------------------------------------------------------------
// Kernel 3: single-plane MFMA GEMM, all-DMA staging. C = A @ Whi^T + bias.
// 128x64 tile, BK=32, 3-buf depth-2 prefetch (vmcnt(6)), 4 waves as 2x2.
// Grid x=mb (W-panel L2 reuse); 32x24=768 (3/CU) and 32x16=512 (2/CU) both
// exactly balanced. 3 DMA loads/thread/stage (A 2, Bh 1); 8 MFMA/wave-step.
// MODE 0: fused epilogue -- q/k: LDS-staged rope -> fp16 qh/kh;
//         v: direct interleaved vth stores.  MODE 1: row-major fp32 + bias.
// ---------------------------------------------------------------------------
template <int MODE>
__global__ __launch_bounds__(256, 3) void gemm2p_kernel(
    const _Float16* __restrict__ Ah,
    const _Float16* __restrict__ Whi,
    int nj0,
    const float* __restrict__ bq, const float* __restrict__ bk,
    const float* __restrict__ bv,
    const float2* __restrict__ tab,
    float* __restrict__ o0f,
    _Float16* __restrict__ qh, _Float16* __restrict__ kh,
    _Float16* __restrict__ vth)
{
    // 36KB: 3 staging bufs (sA 8K | sBh 4K each); MODE0 epilogue reuses the
    // first 32KB as a 128x64 fp32 tile.
    __shared__ __align__(16) char smem[36864];
    _Float16 (*sA )[4096] = (_Float16(*)[4096])(smem);
    _Float16 (*sBh)[2048] = (_Float16(*)[2048])(smem + 24576);

    const int tid  = threadIdx.x;
    const int w    = tid >> 6, lane = tid & 63;
    const int quad = lane >> 4, l15 = lane & 15;
    const int wm = w >> 1, wn = w & 1;
    const int mb   = blockIdx.x;          // x = row tile (W-panel L2 reuse)
    const int nblk = blockIdx.y;
    const int nj   = nj0 + nblk;

    const _Float16* AB = Ah + (size_t)mb * 32 * 4096;
    const size_t woff = (size_t)(nj >> 1) * 32 * 4096 + (size_t)(nj & 1) * 2048;
    const _Float16* WhiB = Whi + woff;

    f32x4 acc[4][2];
#pragma unroll
    for (int mt = 0; mt < 4; ++mt)
#pragma unroll
        for (int nt = 0; nt < 2; ++nt) {
            f32x4 z = {0.f, 0.f, 0.f, 0.f};
            acc[mt][nt] = z;
        }

#define GEMM_STAGE(buf, kbl)                                                  \
    {                                                                         \
        const _Float16* ga = AB   + (size_t)(kbl) * 4096;                     \
        const _Float16* gh = WhiB + (size_t)(kbl) * 4096;                     \
        int cb = w * 64;                                                      \
        async_copy16(&sA [buf][cb * 8],         ga + (size_t)(cb + lane) * 8);        \
        async_copy16(&sA [buf][(cb + 256) * 8], ga + (size_t)(cb + 256 + lane) * 8);  \
        async_copy16(&sBh[buf][cb * 8],         gh + (size_t)(cb + lane) * 8);        \
    }

    GEMM_STAGE(0, 0);
    GEMM_STAGE(1, 1);

    for (int kb = 0; kb < 32; ++kb) {
        const int cur = kb % 3;
        if (kb + 2 < 32) {
            GEMM_STAGE((kb + 2) % 3, kb + 2);
            VMCNT(6);           // stage(kb) done; kb+1, kb+2 in flight
        } else if (kb + 1 < 32) {
            VMCNT(3);           // stage(kb) done; kb+1 in flight
        } else {
            VMCNT(0);
        }
        wg_barrier();

        half8_t af[4], bf[2];
#pragma unroll
        for (int mt = 0; mt < 4; ++mt)
            af[mt] = *(const half8_t*)&sA[cur][(((wm * 4 + mt) * 64) + lane) * 8];
#pragma unroll
        for (int nt = 0; nt < 2; ++nt)
            bf[nt] = *(const half8_t*)&sBh[cur][(((wn * 2 + nt) * 64) + lane) * 8];
#pragma unroll
        for (int mt = 0; mt < 4; ++mt)
#pragma unroll
            for (int nt = 0; nt < 2; ++nt)
                acc[mt][nt] = __builtin_amdgcn_mfma_f32_16x16x32_f16(af[mt], bf[nt], acc[mt][nt], 0, 0, 0);
        LGKMCNT0();             // LDS reads of buf[cur] retired
        wg_barrier();           // safe for stage(kb+3) to overwrite buf[cur]
    }

    if constexpr (MODE == 0) {
        // kind: 0=q (rope, scale), 1=k (rope), 2=v (direct interleave)
        const float* bias; int hh, kind;
        if (nj < 16)      { bias = bq; hh = nj;      kind = 0; }
        else if (nj < 20) { bias = bk; hh = nj - 16; kind = 1; }
        else              { bias = bv; hh = nj - 20; kind = 2; }
        const int b_ = mb >> 4;
        float bias2[2];
#pragma unroll
        for (int nt = 0; nt < 2; ++nt)
            bias2[nt] = bias[hh * 64 + wn * 32 + nt * 16 + l15];

        if (kind == 2) {
            // lane (quad,l15), mt-pair j: one vth unit per (j,nt):
            // u = 2*wm+j, dt = 2*wn+nt, keys {32u+4quad+r, +16+r} = acc rows.
            const int bhk = b_ * NKV + hh;
            const int kt2 = mb & 15;
            _Float16* base = vth + (size_t)(bhk * 16 + kt2) * 1024 * 8;
#pragma unroll
            for (int j = 0; j < 2; ++j)
#pragma unroll
                for (int nt = 0; nt < 2; ++nt) {
                    int u = wm * 2 + j, dt = wn * 2 + nt;
                    half8_t hv;
#pragma unroll
                    for (int r = 0; r < 4; ++r) {
                        hv[r]     = (_Float16)(acc[2 * j][nt][r]     + bias2[nt]);
                        hv[4 + r] = (_Float16)(acc[2 * j + 1][nt][r] + bias2[nt]);
                    }
                    int c = u * 256 + dt * 64 + quad * 16 + l15;
                    *(half8_t*)(base + (size_t)c * 8) = hv;
                }
        } else {
            // stage 128x64 fp32 tile (swizzled: col ^ ((row>>2)&7)<<2)
            float* tile = (float*)smem;
#pragma unroll
            for (int mt = 0; mt < 4; ++mt)
#pragma unroll
                for (int nt = 0; nt < 2; ++nt)
#pragma unroll
                    for (int r = 0; r < 4; ++r) {
                        int rr  = wm * 64 + mt * 16 + quad * 4 + r;
                        int col = wn * 32 + nt * 16 + l15;
                        int sc_ = col ^ (((rr >> 2) & 7) << 2);
                        tile[rr * 64 + sc_] = acc[mt][nt][r] + bias2[nt];
                    }
            __syncthreads();
            // rope: thread = (row rr, half ih); i = 16*ih + ii, ii=0..15
            const int rr = tid >> 1, ih = tid & 1;
            const int t_ = (mb & 15) * 128 + rr;
            const int swz = ((rr >> 2) & 7) << 2;
            const float* trow = tile + rr * 64;
            const float sc = (kind == 0) ? 0.125f : 1.0f;
            _Float16* dst = ((kind == 0) ? qh : kh) +
                ((size_t)(b_ * ((kind == 0) ? NH : NKV) + hh) * T_ + t_) * 64;
            half8_t lo0, lo1, hi0, hi1;
#pragma unroll
            for (int ii = 0; ii < 16; ++ii) {
                int i = ih * 16 + ii;
                float2 cs = tab[t_ * 32 + i];
                float x0 = trow[i ^ swz];
                float x1 = trow[(i + 32) ^ swz];
                float xe = trow[(2 * i) ^ swz];
                float xo = trow[(2 * i + 1) ^ swz];
                float olo = (x0 * cs.x - xo * cs.y) * sc;
                float ohi = (x1 * cs.x + xe * cs.y) * sc;
                if (ii < 8) { lo0[ii] = (_Float16)olo; hi0[ii] = (_Float16)ohi; }
                else        { lo1[ii - 8] = (_Float16)olo; hi1[ii - 8] = (_Float16)ohi; }
            }
            *(half8_t*)(dst + ih * 16)          = lo0;
            *(half8_t*)(dst + ih * 16 + 8)      = lo1;
            *(half8_t*)(dst + 32 + ih * 16)     = hi0;
            *(half8_t*)(dst + 32 + ih * 16 + 8) = hi1;
        }
    } else {
        const int m0 = mb * 128;
        int n0 = nblk * 64 + wn * 32;
#pragma unroll
        for (int mt = 0; mt < 4; ++mt)
#pragma unroll
            for (int r = 0; r < 4; ++r) {
                int m = m0 + wm * 64 + mt * 16 + quad * 4 + r;
#pragma unroll
                for (int nt = 0; nt < 2; ++nt) {
                    int n = n0 + nt * 16 + l15;
                    o0f[(size_t)m * 1024 + n] = acc[mt][nt][r] + bq[n];
                }
            }
    }
#undef GEMM_STAGE
}

// ---------------------------------------------------------------------------
// Kernel 6: flash attention, 128 q/block, 32 q/wave, KVBLK=128, PV K=32
// (r15: 51.3us, 0 conflicts). Unchanged.
// ---------------------------------------------------------------------------
__global__ __launch_bounds__(256, 2) void attn_kernel(
    const _Float16* __restrict__ qh, const _Float16* __restrict__ kh,
    const _Float16* __restrict__ vth, _Float16* __restrict__ ctx_h)
{
    __shared__ _Float16 Ks[2][8192];
    __shared__ _Float16 Vs[2][8192];

    const int qt = blockIdx.x;          // 0..15 (128-q tiles)
    const int bh = blockIdx.y;          // 0..31
    const int b  = bh >> 4, h = bh & 15, hk = h >> 2;
    const int tid  = threadIdx.x;
    const int w    = tid >> 6;
    const int lane = tid & 63;
    const int quad = lane >> 4, l15 = lane & 15;

    // Q B-frags for 2 strips of 16 q-rows (q pre-scaled by 0.125 at rope)
    half8_t aq0[2], aq1[2];
#pragma unroll
    for (int s = 0; s < 2; ++s) {
        const _Float16* Qb = qh +
            ((size_t)(b * NH + h) * T_ + qt * 128 + w * 32 + s * 16 + l15) * 64 + quad * 8;
        aq0[s] = *(const half8_t*)(Qb);
        aq1[s] = *(const half8_t*)(Qb + 32);
    }
    // Force Q loads resolved here -> no compiler vmcnt waits inside the loop.
    asm volatile("" :: "v"(aq0[0]), "v"(aq0[1]), "v"(aq1[0]), "v"(aq1[1]));

    const _Float16* Kb = kh  + (size_t)(b * NKV + hk) * (T_ * 64);
    const _Float16* Vb = vth + (size_t)(b * NKV + hk) * (64 * T_);

    // Stage one 128-key tile-pair: K 1024 chunks + V 1024 chunks, 8 DMA/thread.
#define ATTN_STAGE(buf, ktile)                                                \
    {                                                                         \
        _Float16* kd = &Ks[buf][0];                                           \
        _Float16* vd = &Vs[buf][0];                                           \
        _Pragma("unroll")                                                     \
        for (int p = 0; p < 4; ++p) {                                         \
            int cb = p * 256 + w * 64;                                        \
            int c  = cb + lane;                                               \
            int kl = c & 15, kq = (c >> 4) & 3, ktt = (c >> 6) & 7, kr = c >> 9; \
            const _Float16* kg = Kb + ((size_t)((ktile) * 128 + ktt * 16 + kl)) * 64 + (kr * 4 + kq) * 8; \
            const _Float16* vg = Vb + ((size_t)(ktile) * 1024 + c) * 8;       \
            async_copy16(kd + cb * 8, kg);                                    \
            async_copy16(vd + cb * 8, vg);                                    \
        }                                                                     \
    }

    float l_i[2] = {0.0f, 0.0f};
    f32x4 o_acc[2][4];
#pragma unroll
    for (int s = 0; s < 2; ++s)
#pragma unroll
        for (int dt = 0; dt < 4; ++dt) { f32x4 z = {0.f,0.f,0.f,0.f}; o_acc[s][dt] = z; }

    ATTN_STAGE(0, 0);

    for (int kt = 0; kt < T_ / 128; ++kt) {
        const int cur = kt & 1;
        if (kt + 1 < T_ / 128) {
            ATTN_STAGE(cur ^ 1, kt + 1);
            VMCNT(8);           // wait stage(cur) only; stage(next) in flight
        } else {
            VMCNT(0);
        }
        wg_barrier();           // buf[cur] ready across all waves

#pragma unroll
        for (int u = 0; u < 4; ++u) {
            // K frags for t=2u, 2u+1: wave-contiguous 1KiB b128 reads
            half8_t ak0[2], ak1[2];
#pragma unroll
            for (int tt = 0; tt < 2; ++tt) {
                const _Float16* kr_ = &Ks[cur][((2 * u + tt) * 64 + lane) * 8];
                ak0[tt] = *(const half8_t*)(kr_);
                ak1[tt] = *(const half8_t*)(kr_ + 4096);
            }
            // V A-frags (16x16x32): av8[dt][j] = V^T[d=16dt+l15][K(quad,j)]
            // with K(q,j) = 32u+4q+j (j<4) / 32u+16+4q+j-4 (j>=4).
            half8_t av8[4];
#pragma unroll
            for (int dt = 0; dt < 4; ++dt)
                av8[dt] = *(const half8_t*)&Vs[cur][((u * 4 + dt) * 64 + lane) * 8];

#pragma unroll
            for (int s = 0; s < 2; ++s) {
                // S^T for both 16-key halves of the 32-key u-group
                f32x4 z0 = {0.f,0.f,0.f,0.f}, z1 = {0.f,0.f,0.f,0.f};
                z0 = __builtin_amdgcn_mfma_f32_16x16x32_f16(ak0[0], aq0[s], z0, 0, 0, 0);
                f32x4 sv0 = __builtin_amdgcn_mfma_f32_16x16x32_f16(ak1[0], aq1[s], z0, 0, 0, 0);
                z1 = __builtin_amdgcn_mfma_f32_16x16x32_f16(ak0[1], aq0[s], z1, 0, 0, 0);
                f32x4 sv1 = __builtin_amdgcn_mfma_f32_16x16x32_f16(ak1[1], aq1[s], z1, 0, 0, 0);
                // P: lane (quad,l15) elem j holds exactly P[K(quad,j)][q=l15]
                float p0 = __expf(sv0[0]), p1 = __expf(sv0[1]);
                float p2 = __expf(sv0[2]), p3 = __expf(sv0[3]);
                float p4 = __expf(sv1[0]), p5 = __expf(sv1[1]);
                float p6 = __expf(sv1[2]), p7 = __expf(sv1[3]);
                l_i[s] += ((p0 + p1) + (p2 + p3)) + ((p4 + p5) + (p6 + p7));
                half8_t pb8;
                pb8[0] = (_Float16)p0; pb8[1] = (_Float16)p1;
                pb8[2] = (_Float16)p2; pb8[3] = (_Float16)p3;
                pb8[4] = (_Float16)p4; pb8[5] = (_Float16)p5;
                pb8[6] = (_Float16)p6; pb8[7] = (_Float16)p7;
#pragma unroll
                for (int dt = 0; dt < 4; ++dt)
                    o_acc[s][dt] = __builtin_amdgcn_mfma_f32_16x16x32_f16(
                        av8[dt], pb8, o_acc[s][dt], 0, 0, 0);
            }
        }
        LGKMCNT0();             // all LDS reads of buf[cur] retired
        wg_barrier();           // safe for next iter's DMA to overwrite
    }

    // epilogue: reduce l across quads, normalize, packed half4 ctx stores.
    const int mb = b * 16 + qt;
#pragma unroll
    for (int s = 0; s < 2; ++s) {
        float l = l_i[s];
        l += __shfl_xor(l, 16);
        l += __shfl_xor(l, 32);
        float inv = 1.0f / l;
#pragma unroll
        for (int dt = 0; dt < 4; ++dt) {
            int kb_ = 2 * h + (dt >> 1);
            int k8  = (2 * dt + (quad >> 1)) & 3;
            size_t idx = (size_t)(mb * 32 + kb_) * 512 + (w * 2 + s) * 64 + k8 * 16 + l15;
            half4_t hv;
#pragma unroll
            for (int r = 0; r < 4; ++r)
                hv[r] = (_Float16)(o_acc[s][dt][r] * inv);
            *(half4_t*)&ctx_h[idx * 8 + 4 * (quad & 1)] = hv;
        }
    }
#undef ATTN_STAGE
}

// ---------------------------------------------------------------------------
extern "C" void kernel_launch(void* const* d_in, const int* in_sizes, int n_in,
                              void* d_out, int out_size, void* d_ws, size_t ws_size,
                              hipStream_t stream)
{
    const float* hs = (const float*)d_in[0];
    const float* Wq = (const float*)d_in[1];
    const float* bq = (const float*)d_in[2];
    const float* Wk = (const float*)d_in[3];
    const float* bk = (const float*)d_in[4];
    const float* Wv = (const float*)d_in[5];
    const float* bv = (const float*)d_in[6];
    const float* Wo = (const float*)d_in[7];
    const float* bo = (const float*)d_in[8];
    float* out = (float*)d_out;

    const size_t MB = 1024 * 1024;
    if (ws_size < 46 * MB) return;

    char* w = (char*)d_ws;
    _Float16* Whi  = (_Float16*)(w);              // 5 MB  [0,5)
    _Float16* hs_h = (_Float16*)(w + 5 * MB);     // 8 MB  [5,13) A chunks
    _Float16* qh   = (_Float16*)(w + 13 * MB);    // 8 MB  [13,21)
    _Float16* kh   = (_Float16*)(w + 21 * MB);    // 2 MB  [21,23)
    _Float16* vth  = (_Float16*)(w + 23 * MB);    // 2 MB  [23,25)
    float2*   tab  = (float2*)(w + 25 * MB);      // 0.5MB [25,25.5)
    // ctx aliases hs_h: A chunks dead once gemm<0> completes; attn (which
    // writes ctx) runs strictly after.
    _Float16* ctx_h = hs_h;

    prep_all_kernel<<<3584, 256, 0, stream>>>(
        tab, Wq, Wk, Wv, Wo, Whi, hs, hs_h);
    gemm2p_kernel<0><<<dim3(32, 24), 256, 0, stream>>>(
        hs_h, Whi, 0, bq, bk, bv, tab, nullptr, qh, kh, vth);
    attn_kernel<<<dim3(T_ / 128, B_ * NH), 256, 0, stream>>>(qh, kh, vth, ctx_h);
    gemm2p_kernel<1><<<dim3(32, 16), 256, 0, stream>>>(
        ctx_h, Whi, 24, bo, nullptr, nullptr, tab, out, nullptr, nullptr, nullptr);
}